// Round 4
// baseline (421.706 us; speedup 1.0000x reference)
//
#include <hip/hip_runtime.h>
#include <hip/hip_bf16.h>

// Problem constants (BertSelfAttention_979252544303)
#define SEQ   2048
#define BATCH 2
#define HID   1024
#define NHEAD 16
#define HDIM  64
#define BH    (BATCH * NHEAD)   // 32 flattened heads

using short8   = __attribute__((ext_vector_type(8))) short;
using floatx4  = __attribute__((ext_vector_type(4))) float;
using floatx16 = __attribute__((ext_vector_type(16))) float;

#define LOG2E 1.44269504f
#define SCALE_LOG2E (0.125f * LOG2E)   // (1/sqrt(64)) * log2(e)

// float -> bf16 (RNE)
static __device__ __forceinline__ unsigned short f2bf(float f) {
    unsigned int u = __builtin_bit_cast(unsigned int, f);
    u += 0x7fffu + ((u >> 16) & 1u);
    return (unsigned short)(u >> 16);
}
static __device__ __forceinline__ float bf2f(unsigned short u) {
    return __builtin_bit_cast(float, (unsigned int)u << 16);
}

#define GLD16(gp, lp)                                                        \
    __builtin_amdgcn_global_load_lds(                                        \
        (const __attribute__((address_space(1))) void*)(gp),                 \
        (__attribute__((address_space(3))) void*)(lp), 16, 0, 0)

// ---------------------------------------------------------------------------
// Prep 1: x fp32 [4096][1024] -> bf16 (straight). 1 float4 per thread.
// ---------------------------------------------------------------------------
__global__ __launch_bounds__(256) void convert_x(
    const float* __restrict__ x, unsigned short* __restrict__ xb)
{
    const int i = blockIdx.x * 256 + threadIdx.x;
    const float4 v = ((const float4*)x)[i];
    ushort4 o;
    o.x = f2bf(v.x); o.y = f2bf(v.y); o.z = f2bf(v.z); o.w = f2bf(v.w);
    ((ushort4*)xb)[i] = o;
}

// ---------------------------------------------------------------------------
// Prep 2: W fp32 [k][n] -> wt bf16 [n][k], tiled transpose. z selects Q/K/V.
// ---------------------------------------------------------------------------
__global__ __launch_bounds__(256) void transpose_w(
    const float* __restrict__ Wq, const float* __restrict__ Wk,
    const float* __restrict__ Wv, unsigned short* __restrict__ wt)
{
    const float* W = (blockIdx.z == 0) ? Wq : (blockIdx.z == 1) ? Wk : Wv;
    unsigned short* out = wt + (size_t)blockIdx.z * HID * HID;
    __shared__ float tile[32][33];
    const int tx = threadIdx.x & 31, ty = threadIdx.x >> 5;
    const int bx = blockIdx.x * 32, by = blockIdx.y * 32;
    #pragma unroll
    for (int j = 0; j < 4; ++j)
        tile[ty + j * 8][tx] = W[(size_t)(by + ty + j * 8) * HID + bx + tx];
    __syncthreads();
    #pragma unroll
    for (int j = 0; j < 4; ++j)
        out[(size_t)(bx + ty + j * 8) * HID + by + tx] = f2bf(tile[tx][ty + j * 8]);
}

// ---------------------------------------------------------------------------
// Prep 3: mask fp32 [B][1][S(q)][S(key)] -> maskT bf16 [B][key][q], * log2e.
// ---------------------------------------------------------------------------
__global__ __launch_bounds__(256) void transpose_mask(
    const float* __restrict__ mask, unsigned short* __restrict__ mt)
{
    const int bz = blockIdx.z;
    __shared__ float tile[32][33];
    const int tx = threadIdx.x & 31, ty = threadIdx.x >> 5;
    const int bx = blockIdx.x * 32;   // key
    const int by = blockIdx.y * 32;   // q
    const float* src = mask + (size_t)bz * SEQ * SEQ;
    unsigned short* dst = mt + (size_t)bz * SEQ * SEQ;
    #pragma unroll
    for (int j = 0; j < 4; ++j)   // tile[q_local][key_local]
        tile[ty + j * 8][tx] = src[(size_t)(by + ty + j * 8) * SEQ + bx + tx];
    __syncthreads();
    #pragma unroll
    for (int j = 0; j < 4; ++j)
        dst[(size_t)(bx + ty + j * 8) * SEQ + by + tx] =
            f2bf(tile[tx][ty + j * 8] * LOG2E);
}

// ---------------------------------------------------------------------------
// Kernel 1: fused QKV projection, bf16 MFMA (m97 structure). Unchanged.
// z: 0=Q, 1=K (out [bh][s][d]), 2=V (out [bh][d][s]).
// ---------------------------------------------------------------------------
__global__ __launch_bounds__(256) void qkv_mfma(
    const unsigned short* __restrict__ xb,
    const unsigned short* __restrict__ wt,
    const float* __restrict__ bq, const float* __restrict__ bk,
    const float* __restrict__ bv,
    unsigned short* __restrict__ ws_out)
{
    const int bn = blockIdx.x;   // 0..7
    const int bm = blockIdx.y;   // 0..31
    const int z  = blockIdx.z;   // 0..2
    const unsigned short* Bt = wt + (size_t)z * HID * HID;
    const float* bias = (z == 0) ? bq : (z == 1) ? bk : bv;
    unsigned short* out = ws_out + (size_t)z * (size_t)BH * SEQ * HDIM;

    const int t    = threadIdx.x;
    const int wave = t >> 6;
    const int lane = t & 63;
    const int l15  = lane & 15;
    const int quad = lane >> 4;
    const int wm   = (wave >> 1) * 64;
    const int wn   = (wave & 1) * 64;

    __shared__ __align__(16) unsigned short As[128 * 32];
    __shared__ __align__(16) unsigned short Bs[128 * 32];

    floatx4 acc[4][4];
    #pragma unroll
    for (int i = 0; i < 4; ++i)
        #pragma unroll
        for (int j = 0; j < 4; ++j)
            acc[i][j] = (floatx4){0.f, 0.f, 0.f, 0.f};

    const int lrow = lane >> 2;
    const int lcol = (lane & 3) * 8;

    for (int kt = 0; kt < HID / 32; ++kt) {
        __syncthreads();
        #pragma unroll
        for (int ee = 0; ee < 2; ++ee) {
            const int e = wave * 2 + ee;
            const unsigned short* ga =
                xb + (size_t)(bm * 128 + e * 16 + lrow) * HID + kt * 32 + lcol;
            const unsigned short* gb =
                Bt + (size_t)(bn * 128 + e * 16 + lrow) * HID + kt * 32 + lcol;
            GLD16(ga, (char*)As + e * 1024);
            GLD16(gb, (char*)Bs + e * 1024);
        }
        __syncthreads();

        short8 af[4], bf[4];
        #pragma unroll
        for (int mt = 0; mt < 4; ++mt)
            af[mt] = *(const short8*)&As[(wm + mt * 16 + l15) * 32 + quad * 8];
        #pragma unroll
        for (int nt = 0; nt < 4; ++nt)
            bf[nt] = *(const short8*)&Bs[(wn + nt * 16 + l15) * 32 + quad * 8];
        #pragma unroll
        for (int mt = 0; mt < 4; ++mt)
            #pragma unroll
            for (int nt = 0; nt < 4; ++nt)
                acc[mt][nt] = __builtin_amdgcn_mfma_f32_16x16x32_bf16(
                    af[mt], bf[nt], acc[mt][nt], 0, 0, 0);
    }

    #pragma unroll
    for (int nt = 0; nt < 4; ++nt) {
        const int n_g = bn * 128 + wn + nt * 16 + l15;
        const float bsv = bias[n_g];
        const int h = n_g >> 6;
        const int d = n_g & 63;
        #pragma unroll
        for (int mt = 0; mt < 4; ++mt) {
            #pragma unroll
            for (int r = 0; r < 4; ++r) {
                const int m_g = bm * 128 + wm + mt * 16 + quad * 4 + r;
                const int s  = m_g >> 1;
                const int bb = m_g & 1;
                const unsigned short val = f2bf(acc[mt][nt][r] + bsv);
                if (z < 2)
                    out[((size_t)(bb * NHEAD + h) * SEQ + s) * HDIM + d] = val;
                else
                    out[((size_t)(bb * NHEAD + h) * HDIM + d) * SEQ + s] = val;
            }
        }
    }
}

// ---------------------------------------------------------------------------
// Kernel 2: flash attention v3 — 32x32x16 MFMA, fixed-shift softmax (no
// running max / rescale: mask <= 0 and |s*scale| small => exp2 fp32-safe,
// mathematically identical after normalization).
// Block = (128 q-rows, head). 4 waves; wave owns 32 q-rows.
// Scores: S^T = K @ Q^T  -> C col = q (lane&31): one softmax row per lane.
// PV:     O = P @ V      -> C col = d (lane&31): coalesced stores.
// q,kp: [bh][s][d] bf16; vt: [bh][d][s] bf16; maskT: [b][key][q] bf16*log2e.
// ---------------------------------------------------------------------------
__global__ __launch_bounds__(256) void attn_v3(
    const unsigned short* __restrict__ q,
    const unsigned short* __restrict__ kp,
    const unsigned short* __restrict__ vt,
    const unsigned short* __restrict__ maskT,
    float* __restrict__ out)
{
    const int qb   = blockIdx.x;   // 0..15 (128 q-rows each)
    const int n    = blockIdx.y;   // 0..31 flattened head
    const int t    = threadIdx.x;
    const int wave = t >> 6;
    const int lane = t & 63;
    const int l31  = lane & 31;
    const int half = lane >> 5;    // 0 or 1
    const int bb   = n >> 4;
    const int hh   = n & 15;

    // rows padded to 72 bf16 (stride 36 words; 16B-aligned for b128)
    __shared__ __align__(16) unsigned short Ks[64][72];   // [key][k]
    __shared__ __align__(16) unsigned short Vs[64][72];   // [d][key]
    __shared__ __align__(16) unsigned short QPs[128][72]; // Q then P (wave bands)

    // ---- stage Q (128 x 64), hoist fragments to registers ----
    const unsigned short* qbase = q + ((size_t)n * SEQ + qb * 128) * HDIM;
    #pragma unroll
    for (int u = 0; u < 4; ++u) {
        const int idx = u * 256 + t;       // 0..1023 uint4 chunks
        const int r = idx >> 3, g = idx & 7;
        *(uint4*)&QPs[r][g * 8] = *(const uint4*)(qbase + r * HDIM + g * 8);
    }
    __syncthreads();

    // B-frag layout (32x32x16): n = lane&31, k = (lane>>5)*8 + j
    short8 Qf[4];
    #pragma unroll
    for (int ks = 0; ks < 4; ++ks)
        Qf[ks] = *(const short8*)&QPs[wave * 32 + l31][ks * 16 + half * 8];

    floatx16 Of[2];
    #pragma unroll
    for (int i = 0; i < 16; ++i) { Of[0][i] = 0.f; Of[1][i] = 0.f; }
    float lst = 0.f;

    const unsigned short* kbase = kp + (size_t)n * SEQ * HDIM;
    const unsigned short* vbase = vt + (size_t)n * HDIM * SEQ;
    // mask column fixed per lane: q_global = qb*128 + wave*32 + l31
    const unsigned short* mbase =
        maskT + (size_t)bb * SEQ * SEQ + qb * 128 + wave * 32 + l31;

    for (int kt = 0; kt < SEQ / 64; ++kt) {
        __syncthreads();   // previous tile fully consumed by all waves
        // ---- stage K (64 keys x 64 k) and V^T (64 d x 64 keys) ----
        #pragma unroll
        for (int u = 0; u < 2; ++u) {
            const int idx = u * 256 + t;   // 0..511
            const int r = idx >> 3, g = idx & 7;
            *(uint4*)&Ks[r][g * 8] =
                *(const uint4*)(kbase + (size_t)(kt * 64 + r) * HDIM + g * 8);
            *(uint4*)&Vs[r][g * 8] =
                *(const uint4*)(vbase + (size_t)r * SEQ + kt * 64 + g * 8);
        }
        __syncthreads();

        // ---- scores: S^T = K @ Q^T, two 32-key subtiles ----
        floatx16 Sf[2];
        #pragma unroll
        for (int sub = 0; sub < 2; ++sub) {
            floatx16 c;
            #pragma unroll
            for (int i = 0; i < 16; ++i) c[i] = 0.f;
            #pragma unroll
            for (int ks = 0; ks < 4; ++ks) {
                short8 a = *(const short8*)&Ks[sub * 32 + l31][ks * 16 + half * 8];
                c = __builtin_amdgcn_mfma_f32_32x32x16_bf16(a, Qf[ks], c, 0, 0, 0);
            }
            Sf[sub] = c;
        }

        // ---- p = exp2(s*scale*log2e + m*log2e); accumulate l; pack P ----
        // C row (key) = (reg&3) + 8*(reg>>2) + 4*half
        #pragma unroll
        for (int sub = 0; sub < 2; ++sub) {
            #pragma unroll
            for (int g = 0; g < 4; ++g) {
                float pv[4];
                #pragma unroll
                for (int j = 0; j < 4; ++j) {
                    const int keyl = sub * 32 + g * 8 + half * 4 + j;
                    const float mv = bf2f(mbase[(size_t)(kt * 64 + keyl) * SEQ]);
                    pv[j] = exp2f(fmaf(Sf[sub][g * 4 + j], SCALE_LOG2E, mv));
                    lst += pv[j];
                }
                ushort4 pk;
                pk.x = f2bf(pv[0]); pk.y = f2bf(pv[1]);
                pk.z = f2bf(pv[2]); pk.w = f2bf(pv[3]);
                // wave-private rows: no barrier needed (ds ops in-order per wave)
                *(ushort4*)&QPs[wave * 32 + l31][sub * 32 + g * 8 + half * 4] = pk;
            }
        }

        // ---- PV: O += P @ V ----
        #pragma unroll
        for (int ks = 0; ks < 4; ++ks) {
            short8 a = *(const short8*)&QPs[wave * 32 + l31][ks * 16 + half * 8];
            #pragma unroll
            for (int dsub = 0; dsub < 2; ++dsub) {
                short8 b = *(const short8*)&Vs[dsub * 32 + l31][ks * 16 + half * 8];
                Of[dsub] = __builtin_amdgcn_mfma_f32_32x32x16_bf16(
                    a, b, Of[dsub], 0, 0, 0);
            }
        }
    }

    // ---- epilogue: normalize, write out[s][b][h*64+d] ----
    lst += __shfl_xor(lst, 32);   // both halves now hold full row sums
    #pragma unroll
    for (int g = 0; g < 4; ++g) {
        #pragma unroll
        for (int j = 0; j < 4; ++j) {
            const int reg = g * 4 + j;
            const int ql  = g * 8 + half * 4 + j;        // q within wave band
            const float linv = 1.0f / __shfl(lst, ql);   // lst lives at lane==q
            const int s_g = qb * 128 + wave * 32 + ql;
            float* orow = out + (size_t)s_g * (BATCH * HID) + bb * HID + hh * 64;
            orow[l31]      = Of[0][reg] * linv;
            orow[32 + l31] = Of[1][reg] * linv;
        }
    }
}

// ---------------------------------------------------------------------------
extern "C" void kernel_launch(void* const* d_in, const int* in_sizes, int n_in,
                              void* d_out, int out_size, void* d_ws, size_t ws_size,
                              hipStream_t stream) {
    const float* x    = (const float*)d_in[0];
    const float* mask = (const float*)d_in[1];
    const float* Wq   = (const float*)d_in[2];
    const float* bq   = (const float*)d_in[3];
    const float* Wk   = (const float*)d_in[4];
    const float* bk   = (const float*)d_in[5];
    const float* Wv   = (const float*)d_in[6];
    const float* bv   = (const float*)d_in[7];
    float* out = (float*)d_out;

    const size_t per = (size_t)BH * SEQ * HDIM;   // 4,194,304 elems (8 MB bf16)
    unsigned short* qw = (unsigned short*)d_ws;   // 8 MB
    unsigned short* kw = qw + per;                // 8 MB
    unsigned short* vw = kw + per;                // 8 MB (V transposed [bh][d][s])
    unsigned short* xb = vw + per;                // 8 MB (x bf16)
    unsigned short* wt = xb + per;                // 6 MB (3x W^T bf16)
    unsigned short* mt = wt + (size_t)3 * HID * HID;  // 16 MB (maskT bf16)

    convert_x<<<dim3(SEQ * BATCH * HID / 4 / 256), dim3(256), 0, stream>>>(x, xb);
    transpose_w<<<dim3(32, 32, 3), dim3(256), 0, stream>>>(Wq, Wk, Wv, wt);
    transpose_mask<<<dim3(SEQ / 32, SEQ / 32, BATCH), dim3(256), 0, stream>>>(mask, mt);

    qkv_mfma<<<dim3(HID / 128, SEQ * BATCH / 128, 3), dim3(256), 0, stream>>>(
        xb, wt, bq, bk, bv, qw);

    attn_v3<<<dim3(SEQ / 128, BH), dim3(256), 0, stream>>>(qw, kw, vw, mt, out);
}

// Round 5
// 257.368 us; speedup vs baseline: 1.6385x; 1.6385x over previous
//
#include <hip/hip_runtime.h>
#include <hip/hip_bf16.h>

// Problem constants (BertSelfAttention_979252544303)
#define SEQ   2048
#define BATCH 2
#define HID   1024
#define NHEAD 16
#define HDIM  64
#define BH    (BATCH * NHEAD)   // 32 flattened heads

using short8   = __attribute__((ext_vector_type(8))) short;
using floatx4  = __attribute__((ext_vector_type(4))) float;

#define LOG2E 1.44269504f
#define SCALE_LOG2E (0.125f * LOG2E)   // (1/sqrt(64)) * log2(e)

// float -> bf16 (RNE)
static __device__ __forceinline__ unsigned short f2bf(float f) {
    unsigned int u = __builtin_bit_cast(unsigned int, f);
    u += 0x7fffu + ((u >> 16) & 1u);
    return (unsigned short)(u >> 16);
}

#define GLD16(gp, lp)                                                        \
    __builtin_amdgcn_global_load_lds(                                        \
        (const __attribute__((address_space(1))) void*)(gp),                 \
        (__attribute__((address_space(3))) void*)(lp), 16, 0, 0)

// ---------------------------------------------------------------------------
// Prep 1: x fp32 [4096][1024] -> bf16 (straight). 1 float4 per thread.
// ---------------------------------------------------------------------------
__global__ __launch_bounds__(256) void convert_x(
    const float* __restrict__ x, unsigned short* __restrict__ xb)
{
    const int i = blockIdx.x * 256 + threadIdx.x;
    const float4 v = ((const float4*)x)[i];
    ushort4 o;
    o.x = f2bf(v.x); o.y = f2bf(v.y); o.z = f2bf(v.z); o.w = f2bf(v.w);
    ((ushort4*)xb)[i] = o;
}

// ---------------------------------------------------------------------------
// Prep 2: W fp32 [k][n] -> wt bf16 [n][k], tiled transpose. z selects Q/K/V.
// ---------------------------------------------------------------------------
__global__ __launch_bounds__(256) void transpose_w(
    const float* __restrict__ Wq, const float* __restrict__ Wk,
    const float* __restrict__ Wv, unsigned short* __restrict__ wt)
{
    const float* W = (blockIdx.z == 0) ? Wq : (blockIdx.z == 1) ? Wk : Wv;
    unsigned short* out = wt + (size_t)blockIdx.z * HID * HID;
    __shared__ float tile[32][33];
    const int tx = threadIdx.x & 31, ty = threadIdx.x >> 5;
    const int bx = blockIdx.x * 32, by = blockIdx.y * 32;
    #pragma unroll
    for (int j = 0; j < 4; ++j)
        tile[ty + j * 8][tx] = W[(size_t)(by + ty + j * 8) * HID + bx + tx];
    __syncthreads();
    #pragma unroll
    for (int j = 0; j < 4; ++j)
        out[(size_t)(bx + ty + j * 8) * HID + by + tx] = f2bf(tile[tx][ty + j * 8]);
}

// ---------------------------------------------------------------------------
// Kernel 1: fused QKV projection, bf16 MFMA (m97 structure). Unchanged (R2).
// z: 0=Q, 1=K (out [bh][s][d]), 2=V (out [bh][d][s]).
// ---------------------------------------------------------------------------
__global__ __launch_bounds__(256) void qkv_mfma(
    const unsigned short* __restrict__ xb,
    const unsigned short* __restrict__ wt,
    const float* __restrict__ bq, const float* __restrict__ bk,
    const float* __restrict__ bv,
    unsigned short* __restrict__ ws_out)
{
    const int bn = blockIdx.x;   // 0..7
    const int bm = blockIdx.y;   // 0..31
    const int z  = blockIdx.z;   // 0..2
    const unsigned short* Bt = wt + (size_t)z * HID * HID;
    const float* bias = (z == 0) ? bq : (z == 1) ? bk : bv;
    unsigned short* out = ws_out + (size_t)z * (size_t)BH * SEQ * HDIM;

    const int t    = threadIdx.x;
    const int wave = t >> 6;
    const int lane = t & 63;
    const int l15  = lane & 15;
    const int quad = lane >> 4;
    const int wm   = (wave >> 1) * 64;
    const int wn   = (wave & 1) * 64;

    __shared__ __align__(16) unsigned short As[128 * 32];
    __shared__ __align__(16) unsigned short Bs[128 * 32];

    floatx4 acc[4][4];
    #pragma unroll
    for (int i = 0; i < 4; ++i)
        #pragma unroll
        for (int j = 0; j < 4; ++j)
            acc[i][j] = (floatx4){0.f, 0.f, 0.f, 0.f};

    const int lrow = lane >> 2;
    const int lcol = (lane & 3) * 8;

    for (int kt = 0; kt < HID / 32; ++kt) {
        __syncthreads();
        #pragma unroll
        for (int ee = 0; ee < 2; ++ee) {
            const int e = wave * 2 + ee;
            const unsigned short* ga =
                xb + (size_t)(bm * 128 + e * 16 + lrow) * HID + kt * 32 + lcol;
            const unsigned short* gb =
                Bt + (size_t)(bn * 128 + e * 16 + lrow) * HID + kt * 32 + lcol;
            GLD16(ga, (char*)As + e * 1024);
            GLD16(gb, (char*)Bs + e * 1024);
        }
        __syncthreads();

        short8 af[4], bf[4];
        #pragma unroll
        for (int mt = 0; mt < 4; ++mt)
            af[mt] = *(const short8*)&As[(wm + mt * 16 + l15) * 32 + quad * 8];
        #pragma unroll
        for (int nt = 0; nt < 4; ++nt)
            bf[nt] = *(const short8*)&Bs[(wn + nt * 16 + l15) * 32 + quad * 8];
        #pragma unroll
        for (int mt = 0; mt < 4; ++mt)
            #pragma unroll
            for (int nt = 0; nt < 4; ++nt)
                acc[mt][nt] = __builtin_amdgcn_mfma_f32_16x16x32_bf16(
                    af[mt], bf[nt], acc[mt][nt], 0, 0, 0);
    }

    #pragma unroll
    for (int nt = 0; nt < 4; ++nt) {
        const int n_g = bn * 128 + wn + nt * 16 + l15;
        const float bsv = bias[n_g];
        const int h = n_g >> 6;
        const int d = n_g & 63;
        #pragma unroll
        for (int mt = 0; mt < 4; ++mt) {
            #pragma unroll
            for (int r = 0; r < 4; ++r) {
                const int m_g = bm * 128 + wm + mt * 16 + quad * 4 + r;
                const int s  = m_g >> 1;
                const int bb = m_g & 1;
                const unsigned short val = f2bf(acc[mt][nt][r] + bsv);
                if (z < 2)
                    out[((size_t)(bb * NHEAD + h) * SEQ + s) * HDIM + d] = val;
                else
                    out[((size_t)(bb * NHEAD + h) * HDIM + d) * SEQ + s] = val;
            }
        }
    }
}

// ---------------------------------------------------------------------------
// Kernel 2: flash attention v4 = R2 structure + fixed-shift softmax + hoisted
// Q frags. 16x16x32 MFMA, block = (64 q-rows, head), 4 waves x 16 q-rows,
// grid 1024. No in-loop cross-lane ops (softmax is per-lane; l reduced in
// epilogue). Mask read as coalesced fp32 float4 in original [q][key] layout.
// q,kp: [bh][s][d] bf16; vt: [bh][d][s] bf16; mask: [B][1][S][S] fp32.
// P buffer doubles as Q staging (Q frags hoisted to regs before loop).
// ---------------------------------------------------------------------------
__global__ __launch_bounds__(256) void attn_v4(
    const unsigned short* __restrict__ q,
    const unsigned short* __restrict__ kp,
    const unsigned short* __restrict__ vt,
    const float* __restrict__ mask,
    float* __restrict__ out)
{
    const int qb   = blockIdx.x;   // 0..31 query tile (64 rows)
    const int n    = blockIdx.y;   // 0..31 flattened head
    const int t    = threadIdx.x;
    const int wave = t >> 6;
    const int lane = t & 63;
    const int l15  = lane & 15;
    const int quad = lane >> 4;
    const int bb   = n >> 4;       // batch
    const int hh   = n & 15;       // head

    // rows padded to 72 bf16 (144 B = 36 banks -> 2-way aliasing, free)
    __shared__ __align__(16) unsigned short Ks[64][72];   // [key][k]
    __shared__ __align__(16) unsigned short Vs[64][72];   // [d][key]
    __shared__ __align__(16) unsigned short Ps[64][72];   // Q staging, then P

    // ---- stage Q tile into Ps, hoist B-frags to registers ----
    const unsigned short* qbase = q + ((size_t)n * SEQ + qb * 64) * HDIM;
    {
        int c = t, r = c >> 3, c8 = (c & 7) * 8;
        *(uint4*)&Ps[r][c8] = *(const uint4*)(qbase + r * HDIM + c8);
        c = t + 256; r = c >> 3; c8 = (c & 7) * 8;
        *(uint4*)&Ps[r][c8] = *(const uint4*)(qbase + r * HDIM + c8);
    }
    __syncthreads();
    short8 Qf[2];
    #pragma unroll
    for (int ks = 0; ks < 2; ++ks)
        Qf[ks] = *(const short8*)&Ps[wave * 16 + l15][ks * 32 + quad * 8];
    // NOTE: after this, each wave only writes/reads its own 16-row band of Ps,
    // so no further block-wide hazard on Ps (in-wave DS ordering suffices).

    floatx4 Of[4];
    #pragma unroll
    for (int nt = 0; nt < 4; ++nt) Of[nt] = (floatx4){0.f, 0.f, 0.f, 0.f};
    float lst = 0.0f;   // per-lane partial row-sum (keys of this quad pattern)

    const int qrow_g = qb * 64 + wave * 16 + l15;
    const float* mrow = mask + ((size_t)bb * SEQ + qrow_g) * SEQ;
    const unsigned short* kbase = kp + (size_t)n * SEQ * HDIM;
    const unsigned short* vbase = vt + (size_t)n * HDIM * SEQ;

    for (int kt = 0; kt < SEQ / 64; ++kt) {
        __syncthreads();   // previous K/V tile fully consumed
        {
            const unsigned short* kb = kbase + (size_t)(kt * 64) * HDIM;
            const unsigned short* vb = vbase + kt * 64;
            int c = t, r = c >> 3, c8 = (c & 7) * 8;
            *(uint4*)&Ks[r][c8] = *(const uint4*)(kb + r * HDIM + c8);
            *(uint4*)&Vs[r][c8] = *(const uint4*)(vb + (size_t)r * SEQ + c8);
            c = t + 256; r = c >> 3; c8 = (c & 7) * 8;
            *(uint4*)&Ks[r][c8] = *(const uint4*)(kb + r * HDIM + c8);
            *(uint4*)&Vs[r][c8] = *(const uint4*)(vb + (size_t)r * SEQ + c8);
        }
        __syncthreads();

        // S^T = K(64x64) @ Q^T(64x16 per wave): A=K rows, B=Q frags (regs)
        floatx4 Sf[4];
        #pragma unroll
        for (int mt = 0; mt < 4; ++mt) {
            floatx4 c = (floatx4){0.f, 0.f, 0.f, 0.f};
            #pragma unroll
            for (int ks = 0; ks < 2; ++ks) {
                short8 a = *(const short8*)&Ks[mt * 16 + l15][ks * 32 + quad * 8];
                c = __builtin_amdgcn_mfma_f32_16x16x32_bf16(a, Qf[ks], c, 0, 0, 0);
            }
            Sf[mt] = c;
        }

        // fixed-shift softmax: p = exp2(s*scale*log2e + m*log2e), no running
        // max (mask <= 0, |s*scale| bounded => fp32-safe; identical after /l)
        #pragma unroll
        for (int mt = 0; mt < 4; ++mt) {
            const float4 m4 = *(const float4*)(mrow + kt * 64 + mt * 16 + quad * 4);
            const float mv[4] = {m4.x, m4.y, m4.z, m4.w};
            float pv[4];
            #pragma unroll
            for (int r = 0; r < 4; ++r) {
                pv[r] = exp2f(fmaf(Sf[mt][r], SCALE_LOG2E, mv[r] * LOG2E));
                lst += pv[r];
            }
            ushort4 pk;
            pk.x = f2bf(pv[0]); pk.y = f2bf(pv[1]);
            pk.z = f2bf(pv[2]); pk.w = f2bf(pv[3]);
            *(ushort4*)&Ps[wave * 16 + l15][mt * 16 + quad * 4] = pk;
        }

        // PV: O(16x64) += P(16x64) @ V(64x64); A=P rows, B=V^T rows
        #pragma unroll
        for (int ks = 0; ks < 2; ++ks) {
            short8 a = *(const short8*)&Ps[wave * 16 + l15][ks * 32 + quad * 8];
            #pragma unroll
            for (int nt = 0; nt < 4; ++nt) {
                short8 b = *(const short8*)&Vs[nt * 16 + l15][ks * 32 + quad * 8];
                Of[nt] = __builtin_amdgcn_mfma_f32_16x16x32_bf16(a, b, Of[nt], 0, 0, 0);
            }
        }
    }

    // ---- epilogue: reduce l across quads, normalize, store ----
    lst += __shfl_xor(lst, 16);
    lst += __shfl_xor(lst, 32);   // lane (any quad, l15) now holds full sum for q=l15
    #pragma unroll
    for (int r = 0; r < 4; ++r) {
        const float lrow = __shfl(lst, quad * 4 + r);   // row q = quad*4+r
        const float inv  = 1.0f / lrow;
        const int s = qb * 64 + wave * 16 + quad * 4 + r;
        float* orow = out + ((size_t)s * BATCH + bb) * HID + hh * 64;
        #pragma unroll
        for (int nt = 0; nt < 4; ++nt)
            orow[nt * 16 + l15] = Of[nt][r] * inv;
    }
}

// ---------------------------------------------------------------------------
extern "C" void kernel_launch(void* const* d_in, const int* in_sizes, int n_in,
                              void* d_out, int out_size, void* d_ws, size_t ws_size,
                              hipStream_t stream) {
    const float* x    = (const float*)d_in[0];
    const float* mask = (const float*)d_in[1];
    const float* Wq   = (const float*)d_in[2];
    const float* bq   = (const float*)d_in[3];
    const float* Wk   = (const float*)d_in[4];
    const float* bk   = (const float*)d_in[5];
    const float* Wv   = (const float*)d_in[6];
    const float* bv   = (const float*)d_in[7];
    float* out = (float*)d_out;

    const size_t per = (size_t)BH * SEQ * HDIM;   // 4,194,304 elems (8 MB bf16)
    unsigned short* qw = (unsigned short*)d_ws;   // 8 MB
    unsigned short* kw = qw + per;                // 8 MB
    unsigned short* vw = kw + per;                // 8 MB (V transposed [bh][d][s])
    unsigned short* xb = vw + per;                // 8 MB (x bf16)
    unsigned short* wt = xb + per;                // 6 MB (3x W^T bf16)

    convert_x<<<dim3(SEQ * BATCH * HID / 4 / 256), dim3(256), 0, stream>>>(x, xb);
    transpose_w<<<dim3(32, 32, 3), dim3(256), 0, stream>>>(Wq, Wk, Wv, wt);

    qkv_mfma<<<dim3(HID / 128, SEQ * BATCH / 128, 3), dim3(256), 0, stream>>>(
        xb, wt, bq, bk, bv, qw);

    attn_v4<<<dim3(SEQ / 64, BH), dim3(256), 0, stream>>>(qw, kw, vw, mask, out);
}